// Round 4
// baseline (94.428 us; speedup 1.0000x reference)
//
#include <hip/hip_runtime.h>
#include <math.h>
#include <stdint.h>

// H[r,t] = (1/128) * sum_l alpha_l * exp(j*pi*r*sin(theta_r_l)) * exp(-j*pi*t*sin(theta_t_l))
// Output: out_size == 1024*1024 -> Re(H).
// Re(H) = A * B^T with K interleaved as (re,im) pairs per ray:
//   A[r][2l]   = C*(ar*cos(phi) - ai*sin(phi)),  phi = pi*r*sin(theta_r_l), C = 1/128
//   A[r][2l+1] = C*(ar*sin(phi) + ai*cos(phi))
//   B[t][2l]   = cos(psi),  psi = pi*t*sin(theta_t_l)
//   B[t][2l+1] = sin(psi)
// A/B tiles generated on the fly into LDS (fragment-linear layout, zero bank
// conflicts by construction); single-buffered, two barriers per K-step.
// fp32 split-K partials (validated numerics), reduced by a second kernel.

#define N_T 1024
#define N_R 1024
#define L_RAYS 8192

#define BM 256
#define BN 128
#define BK 32
#define SPLITK 16
#define RAYS_PER_BLK 512   // L_RAYS / SPLITK
#define KSTEPS 32          // RAYS_PER_BLK*2 / BK

typedef __attribute__((ext_vector_type(8))) short bf16x8;
typedef __attribute__((ext_vector_type(4))) float f32x4;
typedef __attribute__((ext_vector_type(4))) unsigned int u32x4;

static __device__ __forceinline__ unsigned short f2bf(float x) {
    unsigned u = __builtin_bit_cast(unsigned, x);
    unsigned r = (u + 0x7FFFu + ((u >> 16) & 1u)) >> 16;
    return (unsigned short)r;
}

// ------------------------------------------------------------- fused GEMM
// grid = 32 tiles (4x8) * SPLITK = 512 blocks (2/CU), 256 threads (4 waves, 2x2).
// LDS fragment-linear: fragment f (16 rows x 32 k) occupies bytes
// [f*1024, f*1024+1024); lane slot s holds row (f*16 + (s&15)),
// k = (s>>4)*8 .. +7 -> matches mfma_f32_16x16x32_bf16 operand layout, so both
// the gen ds_write_b128 and the fragment ds_read_b128 are lane-linear
// (lane i <-> byte i*16): zero bank conflicts.
__global__ __launch_bounds__(256, 2) void fused_gemm_kernel(
    const float* __restrict__ alpha_re, const float* __restrict__ alpha_im,
    const float* __restrict__ theta_t, const float* __restrict__ theta_r,
    float* __restrict__ Pout)  // [SPLITK][N_R][N_T] fp32 partials
{
    __shared__ unsigned short As[BM * BK];   // 16 KB: frags 0..15 (rows)
    __shared__ unsigned short Bs[BN * BK];   // 8 KB:  frags 0..7  (cols)
    __shared__ float4 sP[RAYS_PER_BLK];      // 8 KB: (sin_r, sin_t, ar*C, ai*C)

    const int tid  = threadIdx.x;
    const int wave = tid >> 6;          // 0..3
    const int lane = tid & 63;
    const int bid  = blockIdx.x;
    const int tile = bid & 31;          // 4x8 tile grid
    const int sk   = bid >> 5;          // split-K slice 0..15
    const int r0 = (tile >> 3) * BM;
    const int c0 = (tile & 7) * BN;

    // per-ray parameters for this K-slice
    for (int i = tid; i < RAYS_PER_BLK; i += 256) {
        const int l = sk * RAYS_PER_BLK + i;
        const float C = 0.0078125f;     // 1/128
        sP[i] = make_float4(sinf(theta_r[l]), sinf(theta_t[l]),
                            alpha_re[l] * C, alpha_im[l] * C);
    }

    f32x4 acc[8][4];
    #pragma unroll
    for (int m = 0; m < 8; ++m)
        #pragma unroll
        for (int n = 0; n < 4; ++n)
            acc[m][n] = (f32x4){0.f, 0.f, 0.f, 0.f};

    const int k8   = lane >> 4;         // k-group 0..3
    const int rsub = lane & 15;         // row within fragment
    const int wr = wave >> 1;           // 0..1: row half (128 rows)
    const int wc = wave & 1;            // 0..1: col half (64 cols)
    const float PI = 3.14159265358979323846f;

    for (int kt = 0; kt < KSTEPS; ++kt) {
        __syncthreads();   // iter 0: sP ready; else: prev reads done (WAR)

        const int lidx = kt * 16 + k8 * 4;   // local ray base for this k-group
        // --- generate A fragments (this wave: frags wave+4q, q=0..3)
        #pragma unroll
        for (int q = 0; q < 4; ++q) {
            const int frag = wave + q * 4;          // 0..15
            const float rw = (float)(r0 + frag * 16 + rsub);
            unsigned o[4];
            #pragma unroll
            for (int j = 0; j < 4; ++j) {
                const float4 p = sP[lidx + j];
                const float x = rw * p.x;
                const float f = x - 2.0f * rintf(0.5f * x);  // mod 2 -> [-1,1]
                float sn, cs;
                __sincosf(PI * f, &sn, &cs);
                const float re = p.z * cs - p.w * sn;
                const float im = p.z * sn + p.w * cs;
                o[j] = (unsigned)f2bf(re) | ((unsigned)f2bf(im) << 16);
            }
            *reinterpret_cast<u32x4*>(reinterpret_cast<char*>(&As[0]) + frag * 1024 + lane * 16)
                = *reinterpret_cast<const u32x4*>(o);
        }
        // --- generate B fragments (this wave: frags wave+4q, q=0..1)
        #pragma unroll
        for (int q = 0; q < 2; ++q) {
            const int frag = wave + q * 4;          // 0..7
            const float tw = (float)(c0 + frag * 16 + rsub);
            unsigned o[4];
            #pragma unroll
            for (int j = 0; j < 4; ++j) {
                const float4 p = sP[lidx + j];
                const float x = tw * p.y;
                const float f = x - 2.0f * rintf(0.5f * x);
                float sn, cs;
                __sincosf(PI * f, &sn, &cs);
                o[j] = (unsigned)f2bf(cs) | ((unsigned)f2bf(sn) << 16);
            }
            *reinterpret_cast<u32x4*>(reinterpret_cast<char*>(&Bs[0]) + frag * 1024 + lane * 16)
                = *reinterpret_cast<const u32x4*>(o);
        }
        __syncthreads();

        // --- consume: 32 MFMAs
        bf16x8 a[8], b[4];
        const char* Ab = reinterpret_cast<const char*>(&As[0]);
        const char* Bb = reinterpret_cast<const char*>(&Bs[0]);
        #pragma unroll
        for (int m = 0; m < 8; ++m)
            a[m] = *reinterpret_cast<const bf16x8*>(Ab + (wr * 8 + m) * 1024 + lane * 16);
        #pragma unroll
        for (int n = 0; n < 4; ++n)
            b[n] = *reinterpret_cast<const bf16x8*>(Bb + (wc * 4 + n) * 1024 + lane * 16);
        #pragma unroll
        for (int m = 0; m < 8; ++m)
            #pragma unroll
            for (int n = 0; n < 4; ++n)
                acc[m][n] = __builtin_amdgcn_mfma_f32_16x16x32_bf16(a[m], b[n], acc[m][n], 0, 0, 0);
    }

    // C/D layout (m89/m91): col = lane&15, row = (lane>>4)*4 + reg
    float* P = Pout + (size_t)sk * (N_R * N_T);
    const int crow0 = r0 + wr * 128 + (lane >> 4) * 4;
    const int ccol0 = c0 + wc * 64 + (lane & 15);
    #pragma unroll
    for (int m = 0; m < 8; ++m)
        #pragma unroll
        for (int n = 0; n < 4; ++n)
            #pragma unroll
            for (int j = 0; j < 4; ++j)
                P[(size_t)(crow0 + m * 16 + j) * N_T + ccol0 + n * 16] = acc[m][n][j];
}

// ------------------------------------------------------------- split-K reduce
__global__ __launch_bounds__(256) void reduce_kernel(
    const f32x4* __restrict__ P, f32x4* __restrict__ out)
{
    const int i = blockIdx.x * 256 + threadIdx.x;   // over N_R*N_T/4
    const int n4 = (N_R * N_T) / 4;
    f32x4 s = P[i];
    #pragma unroll
    for (int sk = 1; sk < SPLITK; ++sk) s += P[(size_t)sk * n4 + i];
    out[i] = s;
}

// ------------------------------------------------------------- fp32 fallback
#define TILE 64
#define KC 32
__global__ __launch_bounds__(256) void geo_channel_fallback(
    const float* __restrict__ alpha_re, const float* __restrict__ alpha_im,
    const float* __restrict__ theta_t, const float* __restrict__ theta_r,
    float* __restrict__ out, int interleaved)
{
    __shared__ float sAr[KC][TILE][2];
    __shared__ float sAt[KC][TILE][2];
    const int tid = threadIdx.x;
    const int bid = blockIdx.x;
    const int r0 = (bid / (N_T / TILE)) * TILE;
    const int t0 = (bid % (N_T / TILE)) * TILE;
    const int tx = tid & 15;
    const int ty = tid >> 4;
    float accRe[4][4] = {{0.f}};
    float accIm[4][4] = {{0.f}};
    const float C = 1.0f / 128.0f;
    const float PI = 3.14159265358979323846f;
    for (int lc = 0; lc < L_RAYS; lc += KC) {
        __syncthreads();
        for (int idx = tid; idx < KC * TILE; idx += 256) {
            const int ll = idx >> 6;
            const int rr = idx & 63;
            const int l = lc + ll;
            const float are = alpha_re[l] * C;
            const float aim = alpha_im[l] * C;
            const float srr = sinf(theta_r[l]);
            const float stt = sinf(theta_t[l]);
            {
                float x = (float)(r0 + rr) * srr;
                float f = x - 2.0f * rintf(0.5f * x);
                float s, c;
                __sincosf(PI * f, &s, &c);
                sAr[ll][rr][0] = are * c - aim * s;
                sAr[ll][rr][1] = are * s + aim * c;
            }
            {
                float x = (float)(t0 + rr) * stt;
                float f = x - 2.0f * rintf(0.5f * x);
                float s, c;
                __sincosf(PI * f, &s, &c);
                sAt[ll][rr][0] = c;
                sAt[ll][rr][1] = s;
            }
        }
        __syncthreads();
        #pragma unroll 4
        for (int ll = 0; ll < KC; ++ll) {
            const float4 arv0 = *reinterpret_cast<const float4*>(&sAr[ll][ty * 4 + 0][0]);
            const float4 arv1 = *reinterpret_cast<const float4*>(&sAr[ll][ty * 4 + 2][0]);
            const float4 atv0 = *reinterpret_cast<const float4*>(&sAt[ll][tx * 4 + 0][0]);
            const float4 atv1 = *reinterpret_cast<const float4*>(&sAt[ll][tx * 4 + 2][0]);
            const float arre[4] = {arv0.x, arv0.z, arv1.x, arv1.z};
            const float arim[4] = {arv0.y, arv0.w, arv1.y, arv1.w};
            const float atre[4] = {atv0.x, atv0.z, atv1.x, atv1.z};
            const float atim[4] = {atv0.y, atv0.w, atv1.y, atv1.w};
            #pragma unroll
            for (int i = 0; i < 4; ++i)
                #pragma unroll
                for (int j = 0; j < 4; ++j) {
                    accRe[i][j] = fmaf(arre[i], atre[j], fmaf(arim[i], atim[j], accRe[i][j]));
                    accIm[i][j] = fmaf(arim[i], atre[j], fmaf(-arre[i], atim[j], accIm[i][j]));
                }
        }
    }
    #pragma unroll
    for (int i = 0; i < 4; ++i) {
        const int r = r0 + ty * 4 + i;
        #pragma unroll
        for (int j = 0; j < 4; ++j) {
            const int t = t0 + tx * 4 + j;
            if (interleaved) {
                out[2 * (r * N_T + t) + 0] = accRe[i][j];
                out[2 * (r * N_T + t) + 1] = accIm[i][j];
            } else {
                out[r * N_T + t] = accRe[i][j];
            }
        }
    }
}

// ------------------------------------------------------------- launch
extern "C" void kernel_launch(void* const* d_in, const int* in_sizes, int n_in,
                              void* d_out, int out_size, void* d_ws, size_t ws_size,
                              hipStream_t stream) {
    const float* alpha_re = (const float*)d_in[0];
    const float* alpha_im = (const float*)d_in[1];
    const float* theta_t  = (const float*)d_in[2];
    const float* theta_r  = (const float*)d_in[3];
    float* out = (float*)d_out;

    const int interleaved = (out_size >= 2 * N_R * N_T) ? 1 : 0;
    const size_t needP = (size_t)SPLITK * N_R * N_T * 4;   // 64 MB fp32 partials

    if (interleaved || ws_size < needP) {
        const int nblocks = (N_R / TILE) * (N_T / TILE);
        geo_channel_fallback<<<nblocks, 256, 0, stream>>>(
            alpha_re, alpha_im, theta_t, theta_r, out, interleaved);
        return;
    }

    float* P = (float*)d_ws;
    fused_gemm_kernel<<<32 * SPLITK, 256, 0, stream>>>(
        alpha_re, alpha_im, theta_t, theta_r, P);
    reduce_kernel<<<(N_R * N_T / 4) / 256, 256, 0, stream>>>(
        (const f32x4*)P, (f32x4*)out);
}

// Round 5
// 87.059 us; speedup vs baseline: 1.0846x; 1.0846x over previous
//
#include <hip/hip_runtime.h>
#include <math.h>
#include <stdint.h>

// H[r,t] = (1/128) * sum_l alpha_l * exp(j*pi*r*sin(theta_r_l)) * exp(-j*pi*t*sin(theta_t_l))
// Output: out_size == 1024*1024 -> Re(H).
// Re(H) = A * B^T with K interleaved as (re,im) pairs per ray:
//   A[r][2l]   = C*(ar*cos(phi) - ai*sin(phi)),  phi = pi*r*sin(theta_r_l), C = 1/128
//   A[r][2l+1] = C*(ar*sin(phi) + ai*cos(phi))
//   B[t][2l]   = cos(psi),  psi = pi*t*sin(theta_t_l)
//   B[t][2l+1] = sin(psi)
// A/B tiles generated on the fly into LDS (fragment-linear layout, zero bank
// conflicts); single-buffered, two barriers per K-step (validated in round 4).
// Trig: phases tracked in REVOLUTIONS (sP holds 0.5*sin(theta)); u - rint(u)
// is Sterbenz-exact; v_sin_f32/v_cos_f32 compute sin/cos(2*pi*u).
// fp32 split-K partials, reduced by a second kernel.

#define N_T 1024
#define N_R 1024
#define L_RAYS 8192

#define BM 128
#define BN 128
#define BK 32
#define NTILES 64          // 8x8 tile grid
#define SPLITK 16
#define RAYS_PER_BLK 512   // L_RAYS / SPLITK
#define KSTEPS 32          // RAYS_PER_BLK*2 / BK

typedef __attribute__((ext_vector_type(8))) short bf16x8;
typedef __attribute__((ext_vector_type(4))) float f32x4;
typedef __attribute__((ext_vector_type(4))) unsigned int u32x4;

// ------------------------------------------------------------- fused GEMM
// grid = 64 tiles * SPLITK = 1024 blocks (~3-4/CU), 256 threads (4 waves, 2x2).
// LDS fragment-linear: fragment f (16 rows x 32 k) occupies bytes
// [f*1024, f*1024+1024); lane slot s holds row (f*16 + (s&15)),
// k = (s>>4)*8 .. +7 -> matches mfma_f32_16x16x32_bf16 operand layout, so both
// the gen ds_write_b128 and the fragment ds_read_b128 are lane-linear
// (lane i <-> byte i*16): zero bank conflicts.
__global__ __launch_bounds__(256, 3) void fused_gemm_kernel(
    const float* __restrict__ alpha_re, const float* __restrict__ alpha_im,
    const float* __restrict__ theta_t, const float* __restrict__ theta_r,
    float* __restrict__ Pout)  // [SPLITK][N_R][N_T] fp32 partials
{
    __shared__ unsigned short As[BM * BK];   // 8 KB: frags 0..7 (row panels)
    __shared__ unsigned short Bs[BN * BK];   // 8 KB: frags 0..7 (col panels)
    __shared__ float4 sP[RAYS_PER_BLK];      // 8 KB: (0.5*sin_r, 0.5*sin_t, ar*C, ai*C)

    const int tid  = threadIdx.x;
    const int wave = tid >> 6;          // 0..3
    const int lane = tid & 63;
    const int bid  = blockIdx.x;
    const int tile = bid & (NTILES - 1);
    const int sk   = bid >> 6;          // split-K slice 0..15
    const int r0 = (tile >> 3) * BM;
    const int c0 = (tile & 7) * BN;

    // per-ray parameters for this K-slice (phase slopes in revolutions/index)
    for (int i = tid; i < RAYS_PER_BLK; i += 256) {
        const int l = sk * RAYS_PER_BLK + i;
        const float C = 0.0078125f;     // 1/128
        sP[i] = make_float4(0.5f * sinf(theta_r[l]), 0.5f * sinf(theta_t[l]),
                            alpha_re[l] * C, alpha_im[l] * C);
    }

    f32x4 acc[4][4];
    #pragma unroll
    for (int m = 0; m < 4; ++m)
        #pragma unroll
        for (int n = 0; n < 4; ++n)
            acc[m][n] = (f32x4){0.f, 0.f, 0.f, 0.f};

    const int k8   = lane >> 4;         // k-group 0..3
    const int rsub = lane & 15;         // row within fragment
    const int wr = wave >> 1;           // 0..1: row half (64 rows)
    const int wc = wave & 1;            // 0..1: col half (64 cols)

    // gen targets: this wave generates A-frags {wave, wave+4}, B-frags same ids
    const float rw0 = (float)(r0 + (wave + 0) * 16 + rsub);
    const float rw1 = (float)(r0 + (wave + 4) * 16 + rsub);
    const float tw0 = (float)(c0 + (wave + 0) * 16 + rsub);
    const float tw1 = (float)(c0 + (wave + 4) * 16 + rsub);

    for (int kt = 0; kt < KSTEPS; ++kt) {
        __syncthreads();   // kt=0: sP ready; kt>0: previous reads done (WAR)

        const int lidx = kt * 16 + k8 * 4;   // local ray base for this k-group
        unsigned oa0[4], oa1[4], ob0[4], ob1[4];
        #pragma unroll
        for (int j = 0; j < 4; ++j) {
            const float4 p = sP[lidx + j];
            {   // A frag wave
                float u = rw0 * p.x;  u -= rintf(u);
                const float sn = __builtin_amdgcn_sinf(u);
                const float cs = __builtin_amdgcn_cosf(u);
                const float re = p.z * cs - p.w * sn;
                const float im = p.z * sn + p.w * cs;
                asm("v_cvt_pk_bf16_f32 %0, %1, %2" : "=v"(oa0[j]) : "v"(re), "v"(im));
            }
            {   // A frag wave+4
                float u = rw1 * p.x;  u -= rintf(u);
                const float sn = __builtin_amdgcn_sinf(u);
                const float cs = __builtin_amdgcn_cosf(u);
                const float re = p.z * cs - p.w * sn;
                const float im = p.z * sn + p.w * cs;
                asm("v_cvt_pk_bf16_f32 %0, %1, %2" : "=v"(oa1[j]) : "v"(re), "v"(im));
            }
            {   // B frag wave
                float u = tw0 * p.y;  u -= rintf(u);
                const float sn = __builtin_amdgcn_sinf(u);
                const float cs = __builtin_amdgcn_cosf(u);
                asm("v_cvt_pk_bf16_f32 %0, %1, %2" : "=v"(ob0[j]) : "v"(cs), "v"(sn));
            }
            {   // B frag wave+4
                float u = tw1 * p.y;  u -= rintf(u);
                const float sn = __builtin_amdgcn_sinf(u);
                const float cs = __builtin_amdgcn_cosf(u);
                asm("v_cvt_pk_bf16_f32 %0, %1, %2" : "=v"(ob1[j]) : "v"(cs), "v"(sn));
            }
        }
        char* Ab = reinterpret_cast<char*>(&As[0]);
        char* Bb = reinterpret_cast<char*>(&Bs[0]);
        *reinterpret_cast<u32x4*>(Ab + (wave + 0) * 1024 + lane * 16) = *reinterpret_cast<const u32x4*>(oa0);
        *reinterpret_cast<u32x4*>(Ab + (wave + 4) * 1024 + lane * 16) = *reinterpret_cast<const u32x4*>(oa1);
        *reinterpret_cast<u32x4*>(Bb + (wave + 0) * 1024 + lane * 16) = *reinterpret_cast<const u32x4*>(ob0);
        *reinterpret_cast<u32x4*>(Bb + (wave + 4) * 1024 + lane * 16) = *reinterpret_cast<const u32x4*>(ob1);
        __syncthreads();

        // --- consume: 16 MFMAs
        bf16x8 a[4], b[4];
        #pragma unroll
        for (int m = 0; m < 4; ++m)
            a[m] = *reinterpret_cast<const bf16x8*>(Ab + (wr * 4 + m) * 1024 + lane * 16);
        #pragma unroll
        for (int n = 0; n < 4; ++n)
            b[n] = *reinterpret_cast<const bf16x8*>(Bb + (wc * 4 + n) * 1024 + lane * 16);
        #pragma unroll
        for (int m = 0; m < 4; ++m)
            #pragma unroll
            for (int n = 0; n < 4; ++n)
                acc[m][n] = __builtin_amdgcn_mfma_f32_16x16x32_bf16(a[m], b[n], acc[m][n], 0, 0, 0);
    }

    // C/D layout (m89/m91): col = lane&15, row = (lane>>4)*4 + reg
    float* P = Pout + (size_t)sk * (N_R * N_T);
    const int crow0 = r0 + wr * 64 + (lane >> 4) * 4;
    const int ccol0 = c0 + wc * 64 + (lane & 15);
    #pragma unroll
    for (int m = 0; m < 4; ++m)
        #pragma unroll
        for (int n = 0; n < 4; ++n)
            #pragma unroll
            for (int j = 0; j < 4; ++j)
                P[(size_t)(crow0 + m * 16 + j) * N_T + ccol0 + n * 16] = acc[m][n][j];
}

// ------------------------------------------------------------- split-K reduce
__global__ __launch_bounds__(256) void reduce_kernel(
    const f32x4* __restrict__ P, f32x4* __restrict__ out)
{
    const int i = blockIdx.x * 256 + threadIdx.x;   // over N_R*N_T/4
    const int n4 = (N_R * N_T) / 4;
    f32x4 s = P[i];
    #pragma unroll
    for (int sk = 1; sk < SPLITK; ++sk) s += P[(size_t)sk * n4 + i];
    out[i] = s;
}

// ------------------------------------------------------------- fp32 fallback
#define TILE 64
#define KC 32
__global__ __launch_bounds__(256) void geo_channel_fallback(
    const float* __restrict__ alpha_re, const float* __restrict__ alpha_im,
    const float* __restrict__ theta_t, const float* __restrict__ theta_r,
    float* __restrict__ out, int interleaved)
{
    __shared__ float sAr[KC][TILE][2];
    __shared__ float sAt[KC][TILE][2];
    const int tid = threadIdx.x;
    const int bid = blockIdx.x;
    const int r0 = (bid / (N_T / TILE)) * TILE;
    const int t0 = (bid % (N_T / TILE)) * TILE;
    const int tx = tid & 15;
    const int ty = tid >> 4;
    float accRe[4][4] = {{0.f}};
    float accIm[4][4] = {{0.f}};
    const float C = 1.0f / 128.0f;
    const float PI = 3.14159265358979323846f;
    for (int lc = 0; lc < L_RAYS; lc += KC) {
        __syncthreads();
        for (int idx = tid; idx < KC * TILE; idx += 256) {
            const int ll = idx >> 6;
            const int rr = idx & 63;
            const int l = lc + ll;
            const float are = alpha_re[l] * C;
            const float aim = alpha_im[l] * C;
            const float srr = sinf(theta_r[l]);
            const float stt = sinf(theta_t[l]);
            {
                float x = (float)(r0 + rr) * srr;
                float f = x - 2.0f * rintf(0.5f * x);
                float s, c;
                __sincosf(PI * f, &s, &c);
                sAr[ll][rr][0] = are * c - aim * s;
                sAr[ll][rr][1] = are * s + aim * c;
            }
            {
                float x = (float)(t0 + rr) * stt;
                float f = x - 2.0f * rintf(0.5f * x);
                float s, c;
                __sincosf(PI * f, &s, &c);
                sAt[ll][rr][0] = c;
                sAt[ll][rr][1] = s;
            }
        }
        __syncthreads();
        #pragma unroll 4
        for (int ll = 0; ll < KC; ++ll) {
            const float4 arv0 = *reinterpret_cast<const float4*>(&sAr[ll][ty * 4 + 0][0]);
            const float4 arv1 = *reinterpret_cast<const float4*>(&sAr[ll][ty * 4 + 2][0]);
            const float4 atv0 = *reinterpret_cast<const float4*>(&sAt[ll][tx * 4 + 0][0]);
            const float4 atv1 = *reinterpret_cast<const float4*>(&sAt[ll][tx * 4 + 2][0]);
            const float arre[4] = {arv0.x, arv0.z, arv1.x, arv1.z};
            const float arim[4] = {arv0.y, arv0.w, arv1.y, arv1.w};
            const float atre[4] = {atv0.x, atv0.z, atv1.x, atv1.z};
            const float atim[4] = {atv0.y, atv0.w, atv1.y, atv1.w};
            #pragma unroll
            for (int i = 0; i < 4; ++i)
                #pragma unroll
                for (int j = 0; j < 4; ++j) {
                    accRe[i][j] = fmaf(arre[i], atre[j], fmaf(arim[i], atim[j], accRe[i][j]));
                    accIm[i][j] = fmaf(arim[i], atre[j], fmaf(-arre[i], atim[j], accIm[i][j]));
                }
        }
    }
    #pragma unroll
    for (int i = 0; i < 4; ++i) {
        const int r = r0 + ty * 4 + i;
        #pragma unroll
        for (int j = 0; j < 4; ++j) {
            const int t = t0 + tx * 4 + j;
            if (interleaved) {
                out[2 * (r * N_T + t) + 0] = accRe[i][j];
                out[2 * (r * N_T + t) + 1] = accIm[i][j];
            } else {
                out[r * N_T + t] = accRe[i][j];
            }
        }
    }
}

// ------------------------------------------------------------- launch
extern "C" void kernel_launch(void* const* d_in, const int* in_sizes, int n_in,
                              void* d_out, int out_size, void* d_ws, size_t ws_size,
                              hipStream_t stream) {
    const float* alpha_re = (const float*)d_in[0];
    const float* alpha_im = (const float*)d_in[1];
    const float* theta_t  = (const float*)d_in[2];
    const float* theta_r  = (const float*)d_in[3];
    float* out = (float*)d_out;

    const int interleaved = (out_size >= 2 * N_R * N_T) ? 1 : 0;
    const size_t needP = (size_t)SPLITK * N_R * N_T * 4;   // 64 MB fp32 partials

    if (interleaved || ws_size < needP) {
        const int nblocks = (N_R / TILE) * (N_T / TILE);
        geo_channel_fallback<<<nblocks, 256, 0, stream>>>(
            alpha_re, alpha_im, theta_t, theta_r, out, interleaved);
        return;
    }

    float* P = (float*)d_ws;
    fused_gemm_kernel<<<NTILES * SPLITK, 256, 0, stream>>>(
        alpha_re, alpha_im, theta_t, theta_r, P);
    reduce_kernel<<<(N_R * N_T / 4) / 256, 256, 0, stream>>>(
        (const f32x4*)P, (f32x4*)out);
}